// Round 1
// baseline (476.162 us; speedup 1.0000x reference)
//
#include <hip/hip_runtime.h>

typedef unsigned short ushort_t;
typedef __attribute__((ext_vector_type(8))) short short8;
typedef __attribute__((ext_vector_type(4))) float f32x4;

#define DEV __device__ __forceinline__

constexpr int B_ = 4, T_ = 2048, D_ = 1024, H_ = 16;
constexpr int M_ = B_ * T_;                 // 8192 rows
constexpr float SCALE_ = 0.125f;            // 1/sqrt(64)
constexpr float LOG2E_ = 1.4426950408889634f;

DEV ushort_t f2bf(float f) {
  union { float f; unsigned u; } c; c.f = f;
  unsigned u = c.u;
  return (ushort_t)((u + 0x7fffu + ((u >> 16) & 1u)) >> 16);
}

DEV void gload_lds16(const void* g, void* l) {
  __builtin_amdgcn_global_load_lds(
      (const __attribute__((address_space(1))) void*)g,
      (__attribute__((address_space(3))) void*)l, 16, 0, 0);
}

// ---------------- fp32 -> bf16 convert ----------------
__global__ void __launch_bounds__(256) f2bf_kernel(
    const float* __restrict__ in, ushort_t* __restrict__ out, int n4) {
  int stride = gridDim.x * blockDim.x;
  for (int i = blockIdx.x * blockDim.x + threadIdx.x; i < n4; i += stride) {
    float4 v = reinterpret_cast<const float4*>(in)[i];
    ushort4 o;
    o.x = f2bf(v.x); o.y = f2bf(v.y); o.z = f2bf(v.z); o.w = f2bf(v.w);
    reinterpret_cast<ushort4*>(out)[i] = o;
  }
}

// ---------------- bf16 GEMM, B^T layout: C[m][n] = sum_k A[m][k]*Bw[n][k] + bias[n]
// A: [M][K] bf16 row-major, Bw: [N][K] bf16 row-major. 128x128 tile, BK=64.
template <bool OUT_BF16>
__global__ void __launch_bounds__(256) gemm_bt(
    const ushort_t* __restrict__ A, const ushort_t* __restrict__ Bw,
    const float* __restrict__ bias, void* __restrict__ Cout,
    int M, int N, int K) {
  __shared__ __align__(16) ushort_t lA[128 * 64];
  __shared__ __align__(16) ushort_t lB[128 * 64];
  const int tid = threadIdx.x;
  const int lane = tid & 63;
  const int w = tid >> 6;
  const int wm = w >> 1, wn = w & 1;
  const int r0 = lane & 15;
  const int g8 = (lane >> 4) * 8;
  const int m0 = blockIdx.y * 128, n0 = blockIdx.x * 128;

  f32x4 acc[4][4] = {};

  for (int k0 = 0; k0 < K; k0 += 64) {
    int flat = tid * 8;
    for (int it = 0; it < 4; ++it) {
      int f = it * 2048 + flat;
      int row = f >> 6, col = f & 63;
      gload_lds16(A + (size_t)(m0 + row) * K + k0 + col, &lA[f]);
      gload_lds16(Bw + (size_t)(n0 + row) * K + k0 + col, &lB[f]);
    }
    __syncthreads();
    for (int kc = 0; kc < 64; kc += 32) {
      short8 aF[4], bF[4];
      for (int mi = 0; mi < 4; ++mi)
        aF[mi] = *(const short8*)&lA[(wm * 64 + mi * 16 + r0) * 64 + kc + g8];
      for (int ni = 0; ni < 4; ++ni)
        bF[ni] = *(const short8*)&lB[(wn * 64 + ni * 16 + r0) * 64 + kc + g8];
      for (int mi = 0; mi < 4; ++mi)
        for (int ni = 0; ni < 4; ++ni)
          acc[mi][ni] = __builtin_amdgcn_mfma_f32_16x16x32_bf16(
              aF[mi], bF[ni], acc[mi][ni], 0, 0, 0);
    }
    __syncthreads();
  }

  const int rg = (lane >> 4) * 4;
  for (int mi = 0; mi < 4; ++mi)
    for (int ni = 0; ni < 4; ++ni) {
      int n = n0 + wn * 64 + ni * 16 + r0;
      float bv = bias[n];
      for (int r = 0; r < 4; ++r) {
        int m = m0 + wm * 64 + mi * 16 + rg + r;
        float v = acc[mi][ni][r] + bv;
        if (OUT_BF16)
          ((ushort_t*)Cout)[(size_t)m * N + n] = f2bf(v);
        else
          ((float*)Cout)[(size_t)m * N + n] = v;
      }
    }
}

// ---------------- causal flash attention ----------------
// qkv: [B*T][3072] bf16 (Q at col 0, K at 1024, V at 2048; head h at h*64)
// O:   [B*T][1024] bf16
__global__ void __launch_bounds__(256) attn_kernel(
    const ushort_t* __restrict__ qkv, ushort_t* __restrict__ O) {
  __shared__ __align__(16) ushort_t lK[64 * 64];     // [kv][d] linear
  __shared__ __align__(16) ushort_t lVT[64 * 72];    // [d][kv] padded
  __shared__ __align__(16) ushort_t lP[4][16 * 72];  // per-wave P tile

  const int tid = threadIdx.x;
  const int lane = tid & 63;
  const int w = tid >> 6;
  const int r0 = lane & 15;
  const int g8 = (lane >> 4) * 8;
  const int rg = (lane >> 4) * 4;
  const int qblk = blockIdx.x;
  const int bh = blockIdx.y;
  const int b = bh >> 4, h = bh & 15;
  const int q0w = qblk * 64 + w * 16;

  // Q fragments (held in registers across the whole kv loop)
  short8 aQ[2];
  for (int kc = 0; kc < 2; ++kc)
    aQ[kc] = *(const short8*)(qkv + (size_t)(b * T_ + q0w + r0) * 3072 +
                              h * 64 + kc * 32 + g8);

  f32x4 accO[4] = {};
  float mR[4], lR[4];
  for (int i = 0; i < 4; ++i) { mR[i] = -1e30f; lR[i] = 0.f; }

  ushort_t* lPw = &lP[w][0];

  for (int kt = 0; kt <= qblk; ++kt) {
    __syncthreads();  // prev-iter readers done before restaging
    // stage K tile (linear, direct-to-LDS)
    for (int it = 0; it < 2; ++it) {
      int f = it * 2048 + tid * 8;
      int row = f >> 6, col = f & 63;
      gload_lds16(qkv + (size_t)(b * T_ + kt * 64 + row) * 3072 + 1024 +
                      h * 64 + col,
                  &lK[f]);
    }
    // stage V transposed into padded LDS (reg path)
    for (int it = 0; it < 2; ++it) {
      int f = it * 2048 + tid * 8;
      int kv = f >> 6, d = f & 63;
      ushort_t tmp[8];
      *(uint4*)tmp = *(const uint4*)(qkv + (size_t)(b * T_ + kt * 64 + kv) * 3072 +
                                     2048 + h * 64 + d);
      for (int j = 0; j < 8; ++j) lVT[(d + j) * 72 + kv] = tmp[j];
    }
    __syncthreads();

    // S = Q K^T   (16q x 64kv per wave)
    f32x4 sA[4] = {};
    for (int kc = 0; kc < 2; ++kc)
      for (int ni = 0; ni < 4; ++ni) {
        short8 bK = *(const short8*)&lK[(ni * 16 + r0) * 64 + kc * 32 + g8];
        sA[ni] = __builtin_amdgcn_mfma_f32_16x16x32_bf16(aQ[kc], bK, sA[ni], 0, 0, 0);
      }

    // mask + scale, online softmax
    float nm[4] = {-1e30f, -1e30f, -1e30f, -1e30f};
    for (int ni = 0; ni < 4; ++ni) {
      int kv = kt * 64 + ni * 16 + r0;
      for (int r = 0; r < 4; ++r) {
        int q = q0w + rg + r;
        float s = sA[ni][r] * SCALE_;
        if (kv > q) s = -1e30f;
        sA[ni][r] = s;
        nm[r] = fmaxf(nm[r], s);
      }
    }
    for (int r = 0; r < 4; ++r)
      for (int off = 1; off < 16; off <<= 1)
        nm[r] = fmaxf(nm[r], __shfl_xor(nm[r], off));

    float fac[4], rs[4];
    for (int r = 0; r < 4; ++r) {
      float newM = fmaxf(mR[r], nm[r]);
      fac[r] = exp2f((mR[r] - newM) * LOG2E_);
      mR[r] = newM;
      rs[r] = 0.f;
    }
    for (int ni = 0; ni < 4; ++ni)
      for (int r = 0; r < 4; ++r) {
        float p = exp2f((sA[ni][r] - mR[r]) * LOG2E_);
        sA[ni][r] = p;
        rs[r] += p;
      }
    for (int r = 0; r < 4; ++r) {
      for (int off = 1; off < 16; off <<= 1) rs[r] += __shfl_xor(rs[r], off);
      lR[r] = lR[r] * fac[r] + rs[r];
    }
    for (int ni = 0; ni < 4; ++ni)
      for (int r = 0; r < 4; ++r) accO[ni][r] *= fac[r];

    // P -> per-wave LDS (bf16), re-fragment as MFMA A operand
    for (int ni = 0; ni < 4; ++ni)
      for (int r = 0; r < 4; ++r)
        lPw[(rg + r) * 72 + ni * 16 + r0] = f2bf(sA[ni][r]);

    // O += P V
    for (int kc = 0; kc < 2; ++kc) {
      short8 aP = *(const short8*)&lPw[r0 * 72 + kc * 32 + g8];
      for (int ni = 0; ni < 4; ++ni) {
        short8 bV = *(const short8*)&lVT[(ni * 16 + r0) * 72 + kc * 32 + g8];
        accO[ni] = __builtin_amdgcn_mfma_f32_16x16x32_bf16(aP, bV, accO[ni], 0, 0, 0);
      }
    }
  }

  // epilogue: normalize, write bf16
  for (int ni = 0; ni < 4; ++ni)
    for (int r = 0; r < 4; ++r) {
      int q = q0w + rg + r;
      float v = accO[ni][r] / lR[r];
      O[(size_t)(b * T_ + q) * 1024 + h * 64 + ni * 16 + r0] = f2bf(v);
    }
}

extern "C" void kernel_launch(void* const* d_in, const int* in_sizes, int n_in,
                              void* d_out, int out_size, void* d_ws, size_t ws_size,
                              hipStream_t stream) {
  const float* x = (const float*)d_in[0];
  const float* Wqkv = (const float*)d_in[1];
  const float* bqkv = (const float*)d_in[2];
  const float* Wproj = (const float*)d_in[3];
  const float* bproj = (const float*)d_in[4];
  float* out = (float*)d_out;

  // workspace layout (bf16 buffers), total ~92.3 MB
  ushort_t* xb = (ushort_t*)d_ws;                       // [8192][1024]
  ushort_t* wqkvb = xb + (size_t)M_ * D_;               // [3072][1024]
  ushort_t* wprojb = wqkvb + (size_t)3 * D_ * D_;       // [1024][1024]
  ushort_t* qkvb = wprojb + (size_t)D_ * D_;            // [8192][3072]
  ushort_t* Ob = qkvb + (size_t)M_ * 3 * D_;            // [8192][1024]

  f2bf_kernel<<<2048, 256, 0, stream>>>(x, xb, M_ * D_ / 4);
  f2bf_kernel<<<2048, 256, 0, stream>>>(Wqkv, wqkvb, 3 * D_ * D_ / 4);
  f2bf_kernel<<<1024, 256, 0, stream>>>(Wproj, wprojb, D_ * D_ / 4);

  gemm_bt<true><<<dim3(3 * D_ / 128, M_ / 128), 256, 0, stream>>>(
      xb, wqkvb, bqkv, qkvb, M_, 3 * D_, D_);

  attn_kernel<<<dim3(T_ / 64, B_ * H_), 256, 0, stream>>>(qkvb, Ob);

  gemm_bt<false><<<dim3(D_ / 128, M_ / 128), 256, 0, stream>>>(
      Ob, wprojb, bproj, out, M_, D_, D_);
}

// Round 2
// 255.084 us; speedup vs baseline: 1.8667x; 1.8667x over previous
//
#include <hip/hip_runtime.h>

typedef unsigned short ushort_t;
typedef __attribute__((ext_vector_type(8))) short short8;
typedef __attribute__((ext_vector_type(4))) float f32x4;

#define DEV __device__ __forceinline__

constexpr int B_ = 4, T_ = 2048, D_ = 1024, H_ = 16;
constexpr int M_ = B_ * T_;                 // 8192 rows
constexpr float LOG2E_ = 1.4426950408889634f;

DEV ushort_t f2bf(float f) {
  union { float f; unsigned u; } c; c.f = f;
  unsigned u = c.u;
  return (ushort_t)((u + 0x7fffu + ((u >> 16) & 1u)) >> 16);
}
DEV float bf2f(ushort_t b) {
  union { unsigned u; float f; } c; c.u = ((unsigned)b) << 16;
  return c.f;
}

DEV void gload_lds16(const void* g, void* l) {
  __builtin_amdgcn_global_load_lds(
      (const __attribute__((address_space(1))) void*)g,
      (__attribute__((address_space(3))) void*)l, 16, 0, 0);
}

// ---------------- fp32 -> bf16 convert ----------------
__global__ void __launch_bounds__(256) f2bf_kernel(
    const float* __restrict__ in, ushort_t* __restrict__ out, int n4) {
  int stride = gridDim.x * blockDim.x;
  for (int i = blockIdx.x * blockDim.x + threadIdx.x; i < n4; i += stride) {
    float4 v = reinterpret_cast<const float4*>(in)[i];
    ushort4 o;
    o.x = f2bf(v.x); o.y = f2bf(v.y); o.z = f2bf(v.z); o.w = f2bf(v.w);
    reinterpret_cast<ushort4*>(out)[i] = o;
  }
}

// ---------------- bf16 GEMM, B^T layout: C[m][n] = sum_k A[m][k]*Bw[n][k] + bias[n]
// A: [M][K] bf16 row-major, Bw: [N][K] bf16 row-major. 128x128 tile, BK=64.
// If VT != nullptr, tiles with n0 >= 2048 write transposed into VT[b][h][d][T].
template <bool OUT_BF16>
__global__ void __launch_bounds__(256) gemm_bt(
    const ushort_t* __restrict__ A, const ushort_t* __restrict__ Bw,
    const float* __restrict__ bias, void* __restrict__ Cout,
    ushort_t* __restrict__ VT, int M, int N, int K, int ldc) {
  __shared__ __align__(16) ushort_t lA[128 * 64];
  __shared__ __align__(16) ushort_t lB[128 * 64];
  const int tid = threadIdx.x;
  const int lane = tid & 63;
  const int w = tid >> 6;
  const int wm = w >> 1, wn = w & 1;
  const int r0 = lane & 15;
  const int g8 = (lane >> 4) * 8;
  const int m0 = blockIdx.y * 128, n0 = blockIdx.x * 128;

  f32x4 acc[4][4] = {};

  for (int k0 = 0; k0 < K; k0 += 64) {
    int flat = tid * 8;
    for (int it = 0; it < 4; ++it) {
      int f = it * 2048 + flat;
      int row = f >> 6, col = f & 63;
      gload_lds16(A + (size_t)(m0 + row) * K + k0 + col, &lA[f]);
      gload_lds16(Bw + (size_t)(n0 + row) * K + k0 + col, &lB[f]);
    }
    __syncthreads();
    __builtin_amdgcn_s_setprio(1);
    for (int kc = 0; kc < 64; kc += 32) {
      short8 aF[4], bF[4];
      for (int mi = 0; mi < 4; ++mi)
        aF[mi] = *(const short8*)&lA[(wm * 64 + mi * 16 + r0) * 64 + kc + g8];
      for (int ni = 0; ni < 4; ++ni)
        bF[ni] = *(const short8*)&lB[(wn * 64 + ni * 16 + r0) * 64 + kc + g8];
      for (int mi = 0; mi < 4; ++mi)
        for (int ni = 0; ni < 4; ++ni)
          acc[mi][ni] = __builtin_amdgcn_mfma_f32_16x16x32_bf16(
              aF[mi], bF[ni], acc[mi][ni], 0, 0, 0);
    }
    __builtin_amdgcn_s_setprio(0);
    __syncthreads();
  }

  const int rg = (lane >> 4) * 4;
  const bool vpath = (VT != nullptr) && (n0 >= 2048);
  if (vpath) {
    for (int mi = 0; mi < 4; ++mi)
      for (int ni = 0; ni < 4; ++ni) {
        int n = n0 + wn * 64 + ni * 16 + r0;
        float bv = bias[n];
        int vcol = n - 2048;
        int hh = vcol >> 6, dd = vcol & 63;
        int m = m0 + wm * 64 + mi * 16 + rg;
        int bb = m >> 11, tt = m & 2047;
        ushort4 o;
        o.x = f2bf(acc[mi][ni][0] + bv);
        o.y = f2bf(acc[mi][ni][1] + bv);
        o.z = f2bf(acc[mi][ni][2] + bv);
        o.w = f2bf(acc[mi][ni][3] + bv);
        *reinterpret_cast<ushort4*>(
            &VT[((size_t)((bb << 4) + hh) * 64 + dd) * (size_t)T_ + tt]) = o;
      }
  } else {
    for (int mi = 0; mi < 4; ++mi)
      for (int ni = 0; ni < 4; ++ni) {
        int n = n0 + wn * 64 + ni * 16 + r0;
        float bv = bias[n];
        for (int r = 0; r < 4; ++r) {
          int m = m0 + wm * 64 + mi * 16 + rg + r;
          float v = acc[mi][ni][r] + bv;
          if (OUT_BF16)
            ((ushort_t*)Cout)[(size_t)m * ldc + n] = f2bf(v);
          else
            ((float*)Cout)[(size_t)m * ldc + n] = v;
        }
      }
  }
}

// ---------------- causal flash attention ----------------
// qk: [B*T][2048] bf16 (Q at col 0, K at col 1024; head h at h*64)
// Vt: [B*H][64][T] bf16 (transposed V)
// O:  [B*T][1024] bf16
// Block x = pair index i in [0,16): processes q-tiles i and 31-i (balanced).
__global__ void __launch_bounds__(256) attn_kernel(
    const ushort_t* __restrict__ qk, const ushort_t* __restrict__ Vt,
    ushort_t* __restrict__ O) {
  __shared__ __align__(16) ushort_t lK[64 * 64];     // [kv][d], chunk-swizzled
  __shared__ __align__(16) ushort_t lVT[64 * 64];    // [d][kv], chunk-swizzled
  __shared__ __align__(16) ushort_t lP[4][16 * 72];  // per-wave P tile (padded)

  const int tid = threadIdx.x;
  const int lane = tid & 63;
  const int w = tid >> 6;
  const int r0 = lane & 15;
  const int p = lane >> 4;
  const int g8 = p * 8;
  const int rg = p * 4;
  const int bh = blockIdx.y;
  const int b = bh >> 4, h = bh & 15;

  ushort_t* lPw = &lP[w][0];

  for (int half = 0; half < 2; ++half) {
    const int qblk = half ? (31 - (int)blockIdx.x) : (int)blockIdx.x;
    const int q0w = qblk * 64 + w * 16;

    // Q fragments, pre-scaled by 1/sqrt(64) = 0.125 (exponent-exact)
    short8 aQ[2];
    for (int kc = 0; kc < 2; ++kc) {
      short8 raw = *(const short8*)(qk + (size_t)(b * T_ + q0w + r0) * 2048 +
                                    h * 64 + kc * 32 + g8);
      short8 sc;
      for (int j = 0; j < 8; ++j)
        sc[j] = (short)f2bf(bf2f((ushort_t)raw[j]) * 0.125f);
      aQ[kc] = sc;
    }

    f32x4 accO[4] = {};
    float mR[4], lR[4];
    for (int i = 0; i < 4; ++i) { mR[i] = -1e30f; lR[i] = 0.f; }

    for (int kt = 0; kt <= qblk; ++kt) {
      __syncthreads();  // prev readers done before restaging
      // stage K tile [64kv][64d] and V^T tile [64d][64kv], source-chunk-swizzled
      for (int it = 0; it < 2; ++it) {
        int f = it * 2048 + tid * 8;
        int row = f >> 6;
        int lch = ((f >> 3) & 7) ^ (row & 7);
        gload_lds16(qk + (size_t)(b * T_ + kt * 64 + row) * 2048 + 1024 +
                        h * 64 + lch * 8,
                    &lK[f]);
        gload_lds16(Vt + ((size_t)bh * 64 + row) * (size_t)T_ + kt * 64 + lch * 8,
                    &lVT[f]);
      }
      __syncthreads();

      // S = Q K^T   (16q x 64kv per wave), swizzled K reads
      f32x4 sA[4] = {};
      __builtin_amdgcn_s_setprio(1);
      for (int kc = 0; kc < 2; ++kc)
        for (int ni = 0; ni < 4; ++ni) {
          int row = ni * 16 + r0;
          int ch = (kc * 4 + p) ^ (row & 7);
          short8 bK = *(const short8*)&lK[row * 64 + ch * 8];
          sA[ni] = __builtin_amdgcn_mfma_f32_16x16x32_bf16(aQ[kc], bK, sA[ni], 0, 0, 0);
        }
      __builtin_amdgcn_s_setprio(0);

      // mask, online softmax
      float nm[4] = {-1e30f, -1e30f, -1e30f, -1e30f};
      for (int ni = 0; ni < 4; ++ni) {
        int kv = kt * 64 + ni * 16 + r0;
        for (int r = 0; r < 4; ++r) {
          int q = q0w + rg + r;
          float s = sA[ni][r];
          if (kv > q) s = -1e30f;
          sA[ni][r] = s;
          nm[r] = fmaxf(nm[r], s);
        }
      }
      for (int r = 0; r < 4; ++r)
        for (int off = 1; off < 16; off <<= 1)
          nm[r] = fmaxf(nm[r], __shfl_xor(nm[r], off));

      float fac[4], rs[4];
      for (int r = 0; r < 4; ++r) {
        float newM = fmaxf(mR[r], nm[r]);
        fac[r] = exp2f((mR[r] - newM) * LOG2E_);
        mR[r] = newM;
        rs[r] = 0.f;
      }
      for (int ni = 0; ni < 4; ++ni)
        for (int r = 0; r < 4; ++r) {
          float pv = exp2f((sA[ni][r] - mR[r]) * LOG2E_);
          sA[ni][r] = pv;
          rs[r] += pv;
        }
      for (int r = 0; r < 4; ++r) {
        for (int off = 1; off < 16; off <<= 1) rs[r] += __shfl_xor(rs[r], off);
        lR[r] = lR[r] * fac[r] + rs[r];
      }
      for (int ni = 0; ni < 4; ++ni)
        for (int r = 0; r < 4; ++r) accO[ni][r] *= fac[r];

      // P -> per-wave LDS (bf16), re-fragment as MFMA A operand
      for (int ni = 0; ni < 4; ++ni)
        for (int r = 0; r < 4; ++r)
          lPw[(rg + r) * 72 + ni * 16 + r0] = f2bf(sA[ni][r]);

      // O += P V  (swizzled V^T reads)
      __builtin_amdgcn_s_setprio(1);
      for (int kc = 0; kc < 2; ++kc) {
        short8 aP = *(const short8*)&lPw[r0 * 72 + kc * 32 + g8];
        for (int ni = 0; ni < 4; ++ni) {
          int row = ni * 16 + r0;
          int ch = (kc * 4 + p) ^ (row & 7);
          short8 bV = *(const short8*)&lVT[row * 64 + ch * 8];
          accO[ni] = __builtin_amdgcn_mfma_f32_16x16x32_bf16(aP, bV, accO[ni], 0, 0, 0);
        }
      }
      __builtin_amdgcn_s_setprio(0);
    }

    // epilogue: normalize, write bf16
    for (int ni = 0; ni < 4; ++ni)
      for (int r = 0; r < 4; ++r) {
        int q = q0w + rg + r;
        float v = accO[ni][r] / lR[r];
        O[(size_t)(b * T_ + q) * 1024 + h * 64 + ni * 16 + r0] = f2bf(v);
      }
  }
}

extern "C" void kernel_launch(void* const* d_in, const int* in_sizes, int n_in,
                              void* d_out, int out_size, void* d_ws, size_t ws_size,
                              hipStream_t stream) {
  const float* x = (const float*)d_in[0];
  const float* Wqkv = (const float*)d_in[1];
  const float* bqkv = (const float*)d_in[2];
  const float* Wproj = (const float*)d_in[3];
  const float* bproj = (const float*)d_in[4];
  float* out = (float*)d_out;

  // workspace layout (bf16 buffers), total ~92.3 MB
  ushort_t* xb = (ushort_t*)d_ws;                       // [8192][1024]
  ushort_t* wqkvb = xb + (size_t)M_ * D_;               // [3072][1024]
  ushort_t* wprojb = wqkvb + (size_t)3 * D_ * D_;       // [1024][1024]
  ushort_t* qkb = wprojb + (size_t)D_ * D_;             // [8192][2048] (Q|K)
  ushort_t* Vt = qkb + (size_t)M_ * 2048;               // [64][64][2048]
  ushort_t* Ob = Vt + (size_t)M_ * D_;                  // [8192][1024]

  f2bf_kernel<<<2048, 256, 0, stream>>>(x, xb, M_ * D_ / 4);
  f2bf_kernel<<<2048, 256, 0, stream>>>(Wqkv, wqkvb, 3 * D_ * D_ / 4);
  f2bf_kernel<<<1024, 256, 0, stream>>>(Wproj, wprojb, D_ * D_ / 4);

  gemm_bt<true><<<dim3(24, 64), 256, 0, stream>>>(
      xb, wqkvb, bqkv, qkb, Vt, M_, 3 * D_, D_, 2048);

  attn_kernel<<<dim3(16, 64), 256, 0, stream>>>(qkb, Vt, Ob);

  gemm_bt<false><<<dim3(8, 64), 256, 0, stream>>>(
      Ob, wprojb, bproj, out, nullptr, M_, D_, D_, D_);
}